// Round 1
// baseline (294.829 us; speedup 1.0000x reference)
//
#include <hip/hip_runtime.h>
#include <math.h>

#define BB 64
#define TT 2048
#define DD 256
#define MM 20
#define TOPK_N 100
#define EPSF 1e-12f

// ---------------- Kernel A: fused 3-way matvec + activations ----------------
// one wave per (b,t) row per iteration; lane i handles x[row, 4i..4i+3]
__global__ __launch_bounds__(256) void preds_kernel(
    const float* __restrict__ x,
    const float* __restrict__ wc, const float* __restrict__ bc,
    const float* __restrict__ ww, const float* __restrict__ bw,
    const float* __restrict__ wo, const float* __restrict__ bo,
    const float* __restrict__ sal,
    float* __restrict__ cp, float* __restrict__ wp, float* __restrict__ op)
{
    const int lane = threadIdx.x & 63;
    const int waveg = blockIdx.x * 4 + (threadIdx.x >> 6);
    const int nwaves = gridDim.x * 4;

    const float4 wc4 = ((const float4*)wc)[lane];
    const float4 ww4 = ((const float4*)ww)[lane];
    const float4 wo4 = ((const float4*)wo)[lane];
    const float bcs = bc[0], bws = bw[0], bos = bo[0];

    for (int row = waveg; row < BB * TT; row += nwaves) {
        const float4 x4 = ((const float4*)(x + (size_t)row * DD))[lane];
        float sc = x4.x * wc4.x + x4.y * wc4.y + x4.z * wc4.z + x4.w * wc4.w;
        float sw = x4.x * ww4.x + x4.y * ww4.y + x4.z * ww4.z + x4.w * ww4.w;
        float so = x4.x * wo4.x + x4.y * wo4.y + x4.z * wo4.z + x4.w * wo4.w;
        #pragma unroll
        for (int m = 32; m >= 1; m >>= 1) {
            sc += __shfl_xor(sc, m, 64);
            sw += __shfl_xor(sw, m, 64);
            so += __shfl_xor(so, m, 64);
        }
        if (lane == 0) {
            const float mask = (sal[row] >= 0.0f) ? 1.0f : 0.0f;
            const float z = sc + bcs;
            const float s = 1.0f / (1.0f + expf(-z));
            cp[row] = s * mask;
            wp[row] = sw + bws;
            op[row] = so + bos;
        }
    }
}

// ---------------- Kernel B: targets + loss partials (one block per b) -------
__global__ __launch_bounds__(256) void targets_kernel(
    const float* __restrict__ boundary, const float* __restrict__ sal,
    const float* __restrict__ cp, const float* __restrict__ wp,
    const float* __restrict__ op, float* __restrict__ partials)
{
    __shared__ int   s_ci[MM];
    __shared__ float s_win[MM], s_off[MM], s_sig[MM];
    __shared__ int   s_rad[MM], s_valid[MM], s_last[MM];
    __shared__ float s_red[4][4];

    const int b = blockIdx.x;
    const int tid = threadIdx.x;

    if (tid < MM) {
        const float b0 = boundary[(b * MM + tid) * 2 + 0];
        const float b1 = boundary[(b * MM + tid) * 2 + 1];
        const int v = (b0 != -1.0f) ? 1 : 0;
        const float b0c = b0 * 0.5f;
        const float b1c = (b1 - 2.0f) * 0.5f;
        const float c = fminf((b0c + b1c) * 0.5f, (float)TT - 0.5f);
        const float w = b1c - b0c;
        const int r = (int)(w * 0.2f);              // trunc like .astype(int32)
        const float sg = ((float)r + 1.0f) * 0.2f;
        const int ci = (int)c;
        s_ci[tid] = ci; s_win[tid] = w; s_off[tid] = c - (float)ci;
        s_sig[tid] = sg; s_rad[tid] = r; s_valid[tid] = v;
    }
    __syncthreads();
    if (tid < MM) {
        int last = s_valid[tid];
        if (last) {  // numpy fancy assignment: last duplicate object wins
            for (int m2 = tid + 1; m2 < MM; ++m2)
                if (s_valid[m2] && s_ci[m2] == s_ci[tid]) { last = 0; break; }
        }
        s_last[tid] = last;
    }
    __syncthreads();

    float cl = 0.0f, wl = 0.0f, ol = 0.0f, cnt = 0.0f;
    if (tid < MM) {
        if (s_valid[tid]) cnt = 1.0f;
        if (s_last[tid]) {
            const int t = s_ci[tid];
            wl = fabsf(wp[b * TT + t] - s_win[tid]);
            ol = fabsf(op[b * TT + t] - s_off[tid]);
        }
    }
    for (int t = tid; t < TT; t += 256) {
        float ctgt = 0.0f;
        for (int m = 0; m < MM; ++m) {
            if (!s_valid[m]) continue;
            const int d = t - s_ci[m];
            const int ad = d < 0 ? -d : d;
            if (ad <= s_rad[m]) {
                const float df = (float)d;
                const float sg = s_sig[m];
                const float g = expf(-(df * df) / (2.0f * sg * sg));
                ctgt = fmaxf(ctgt, g);
            }
        }
        const float p = cp[b * TT + t];
        const float mask = (sal[b * TT + t] >= 0.0f) ? 1.0f : 0.0f;
        const float pos = (ctgt == 1.0f) ? 1.0f : 0.0f;
        const float om = 1.0f - p;
        const float pl = -logf(p + EPSF) * om * om * pos;
        const float q = 1.0f - ctgt;
        const float q2 = q * q;
        const float nl = -logf(1.0f - p + EPSF) * p * p * (q2 * q2);
        cl += (pl + nl) * mask;
    }
    #pragma unroll
    for (int m = 32; m >= 1; m >>= 1) {
        cl  += __shfl_xor(cl,  m, 64);
        wl  += __shfl_xor(wl,  m, 64);
        ol  += __shfl_xor(ol,  m, 64);
        cnt += __shfl_xor(cnt, m, 64);
    }
    if ((tid & 63) == 0) {
        const int w = tid >> 6;
        s_red[w][0] = cl; s_red[w][1] = wl; s_red[w][2] = ol; s_red[w][3] = cnt;
    }
    __syncthreads();
    if (tid == 0) {
        float a = 0, b2 = 0, c = 0, d = 0;
        for (int w = 0; w < 4; ++w) {
            a += s_red[w][0]; b2 += s_red[w][1]; c += s_red[w][2]; d += s_red[w][3];
        }
        partials[b * 4 + 0] = a; partials[b * 4 + 1] = b2;
        partials[b * 4 + 2] = c; partials[b * 4 + 3] = d;
    }
}

// ---------------- Kernel C: deterministic finalize --------------------------
__global__ void finalize_kernel(const float* __restrict__ partials, float* __restrict__ out)
{
    if (threadIdx.x == 0 && blockIdx.x == 0) {
        float cl = 0, wl = 0, ol = 0, cnt = 0;
        for (int i = 0; i < BB; ++i) {
            cl += partials[i * 4 + 0]; wl += partials[i * 4 + 1];
            ol += partials[i * 4 + 2]; cnt += partials[i * 4 + 3];
        }
        out[BB * TOPK_N * 3 + 0] = cl / cnt;
        out[BB * TOPK_N * 3 + 1] = 0.1f * wl / cnt;
        out[BB * TOPK_N * 3 + 2] = ol / cnt;
    }
}

// ---------------- Kernel D: local-max filter + exact top-100 ----------------
__global__ __launch_bounds__(256) void topk_kernel(
    const float* __restrict__ cp, const float* __restrict__ wp,
    const float* __restrict__ op, float* __restrict__ out)
{
    __shared__ unsigned long long keys[TT];
    const int b = blockIdx.x;
    const int tid = threadIdx.x;
    const float* row = cp + b * TT;

    for (int t = tid; t < TT; t += 256) {
        const float p = row[t];
        const float l = (t > 0) ? row[t - 1] : -1.0f;       // pad = -inf; cp>=0 so -1 works
        const float r = (t < TT - 1) ? row[t + 1] : -1.0f;
        const float hm = fmaxf(p, fmaxf(l, r));
        const float v = (hm == p) ? p : 0.0f;
        // v >= 0 -> IEEE bits are order-monotonic. Tie-break: lowest index first.
        keys[t] = ((unsigned long long)__float_as_uint(v) << 32)
                | (unsigned int)(0xFFFFFFFFu - (unsigned int)t);
    }
    __syncthreads();

    // bitonic sort, descending
    for (int k = 2; k <= TT; k <<= 1) {
        for (int j = k >> 1; j >= 1; j >>= 1) {
            for (int i = tid; i < TT; i += 256) {
                const int p = i ^ j;
                if (p > i) {
                    const bool desc = ((i & k) == 0);
                    const unsigned long long a = keys[i], bk = keys[p];
                    const bool sw = desc ? (a < bk) : (a > bk);
                    if (sw) { keys[i] = bk; keys[p] = a; }
                }
            }
            __syncthreads();
        }
    }

    if (tid < TOPK_N) {
        const unsigned long long kk = keys[tid];
        const int idx = (int)(0xFFFFFFFFu - (unsigned int)kk);
        const float score = __uint_as_float((unsigned int)(kk >> 32));
        const float off = fmaxf(op[b * TT + idx], 0.0f);
        const float center = (float)idx + off;
        const float win = fmaxf(wp[b * TT + idx], 0.0f);
        const float lo = fminf(fmaxf(center - win * 0.5f, 0.0f), (float)TT - 1.0f) * 2.0f;
        const float hi = fminf(fmaxf(center + win * 0.5f, 0.0f), (float)TT - 1.0f) * 2.0f + 2.0f;
        float* o = out + (b * TOPK_N + tid) * 3;
        o[0] = lo; o[1] = hi; o[2] = score;
    }
}

extern "C" void kernel_launch(void* const* d_in, const int* in_sizes, int n_in,
                              void* d_out, int out_size, void* d_ws, size_t ws_size,
                              hipStream_t stream) {
    const float* x   = (const float*)d_in[0];
    const float* wc  = (const float*)d_in[1];
    const float* bc  = (const float*)d_in[2];
    const float* ww  = (const float*)d_in[3];
    const float* bw  = (const float*)d_in[4];
    const float* wo  = (const float*)d_in[5];
    const float* bo  = (const float*)d_in[6];
    const float* sal = (const float*)d_in[7];
    const float* bnd = (const float*)d_in[8];
    float* out = (float*)d_out;

    float* ws = (float*)d_ws;
    float* cp = ws;                     // B*T
    float* wp = ws + BB * TT;           // B*T
    float* op = ws + 2 * BB * TT;       // B*T
    float* partials = ws + 3 * BB * TT; // B*4

    // A: 131072 rows, 4 waves/block, 8 rows/wave -> 4096 blocks
    preds_kernel<<<4096, 256, 0, stream>>>(x, wc, bc, ww, bw, wo, bo, sal, cp, wp, op);
    targets_kernel<<<BB, 256, 0, stream>>>(bnd, sal, cp, wp, op, partials);
    finalize_kernel<<<1, 64, 0, stream>>>(partials, out);
    topk_kernel<<<BB, 256, 0, stream>>>(cp, wp, op, out);
}

// Round 2
// 260.857 us; speedup vs baseline: 1.1302x; 1.1302x over previous
//
#include <hip/hip_runtime.h>
#include <math.h>

#define BB 64
#define TT 2048
#define DD 256
#define MM 20
#define TOPK_N 100
#define EPSF 1e-12f

// ---------------- Kernel A: fused 3-way matvec + activations ----------------
// 16 lanes per row, 4 rows per wave. Each lane preloads 12 weight float4s
// (3 preds x 4 k-chunks) and accumulates 3 dot partials over 16 elements,
// then a 4-step butterfly within the 16-lane group finishes the dot.
// 12 shuffles per 4 rows (vs 18/row in the 64-lane layout).
__global__ __launch_bounds__(256) void preds_kernel(
    const float* __restrict__ x,
    const float* __restrict__ wc, const float* __restrict__ bc,
    const float* __restrict__ ww, const float* __restrict__ bw,
    const float* __restrict__ wo, const float* __restrict__ bo,
    const float* __restrict__ sal,
    float* __restrict__ cp, float* __restrict__ wp, float* __restrict__ op)
{
    const int lane = threadIdx.x & 63;
    const int sub  = lane >> 4;    // row within the wave's 4-row group
    const int cg   = lane & 15;    // column group (16 lanes cover 64 float4s / 4 k-chunks)
    const int waveg  = blockIdx.x * 4 + (threadIdx.x >> 6);
    const int nwaves = gridDim.x * 4;

    float4 wc4[4], ww4[4], wo4[4];
    #pragma unroll
    for (int k = 0; k < 4; ++k) {
        wc4[k] = ((const float4*)wc)[k * 16 + cg];
        ww4[k] = ((const float4*)ww)[k * 16 + cg];
        wo4[k] = ((const float4*)wo)[k * 16 + cg];
    }
    const float bcs = bc[0], bws = bw[0], bos = bo[0];

    const int ngroups = BB * TT / 4;   // 32768 groups of 4 rows
    for (int g = waveg; g < ngroups; g += nwaves) {
        const int row = g * 4 + sub;
        const float4* xr = (const float4*)(x + (size_t)row * DD);
        float sc = 0.0f, sw = 0.0f, so = 0.0f;
        #pragma unroll
        for (int k = 0; k < 4; ++k) {
            const float4 x4 = xr[k * 16 + cg];
            sc += x4.x * wc4[k].x + x4.y * wc4[k].y + x4.z * wc4[k].z + x4.w * wc4[k].w;
            sw += x4.x * ww4[k].x + x4.y * ww4[k].y + x4.z * ww4[k].z + x4.w * ww4[k].w;
            so += x4.x * wo4[k].x + x4.y * wo4[k].y + x4.z * wo4[k].z + x4.w * wo4[k].w;
        }
        #pragma unroll
        for (int m = 8; m >= 1; m >>= 1) {   // butterfly within 16-lane group
            sc += __shfl_xor(sc, m, 64);
            sw += __shfl_xor(sw, m, 64);
            so += __shfl_xor(so, m, 64);
        }
        if (cg == 0) {
            const float mask = (sal[row] >= 0.0f) ? 1.0f : 0.0f;
            const float s = 1.0f / (1.0f + expf(-(sc + bcs)));
            cp[row] = s * mask;
            wp[row] = sw + bws;
            op[row] = so + bos;
        }
    }
}

// ---------------- Kernel B: targets + loss partials (one block per b) -------
__global__ __launch_bounds__(256) void targets_kernel(
    const float* __restrict__ boundary, const float* __restrict__ sal,
    const float* __restrict__ cp, const float* __restrict__ wp,
    const float* __restrict__ op, float* __restrict__ partials)
{
    __shared__ int   s_ci[MM];
    __shared__ float s_win[MM], s_off[MM], s_sig[MM];
    __shared__ int   s_rad[MM], s_valid[MM], s_last[MM];
    __shared__ float s_red[4][4];

    const int b = blockIdx.x;
    const int tid = threadIdx.x;

    if (tid < MM) {
        const float b0 = boundary[(b * MM + tid) * 2 + 0];
        const float b1 = boundary[(b * MM + tid) * 2 + 1];
        const int v = (b0 != -1.0f) ? 1 : 0;
        const float b0c = b0 * 0.5f;
        const float b1c = (b1 - 2.0f) * 0.5f;
        const float c = fminf((b0c + b1c) * 0.5f, (float)TT - 0.5f);
        const float w = b1c - b0c;
        const int r = (int)(w * 0.2f);              // trunc like .astype(int32)
        const float sg = ((float)r + 1.0f) * 0.2f;
        const int ci = (int)c;
        s_ci[tid] = ci; s_win[tid] = w; s_off[tid] = c - (float)ci;
        s_sig[tid] = sg; s_rad[tid] = r; s_valid[tid] = v;
    }
    __syncthreads();
    if (tid < MM) {
        int last = s_valid[tid];
        if (last) {  // numpy fancy assignment: last duplicate object wins
            for (int m2 = tid + 1; m2 < MM; ++m2)
                if (s_valid[m2] && s_ci[m2] == s_ci[tid]) { last = 0; break; }
        }
        s_last[tid] = last;
    }
    __syncthreads();

    float cl = 0.0f, wl = 0.0f, ol = 0.0f, cnt = 0.0f;
    if (tid < MM) {
        if (s_valid[tid]) cnt = 1.0f;
        if (s_last[tid]) {
            const int t = s_ci[tid];
            wl = fabsf(wp[b * TT + t] - s_win[tid]);
            ol = fabsf(op[b * TT + t] - s_off[tid]);
        }
    }
    for (int t = tid; t < TT; t += 256) {
        float ctgt = 0.0f;
        for (int m = 0; m < MM; ++m) {
            if (!s_valid[m]) continue;
            const int d = t - s_ci[m];
            const int ad = d < 0 ? -d : d;
            if (ad <= s_rad[m]) {
                const float df = (float)d;
                const float sg = s_sig[m];
                const float g = expf(-(df * df) / (2.0f * sg * sg));
                ctgt = fmaxf(ctgt, g);
            }
        }
        const float p = cp[b * TT + t];
        const float mask = (sal[b * TT + t] >= 0.0f) ? 1.0f : 0.0f;
        const float pos = (ctgt == 1.0f) ? 1.0f : 0.0f;
        const float om = 1.0f - p;
        const float pl = -logf(p + EPSF) * om * om * pos;
        const float q = 1.0f - ctgt;
        const float q2 = q * q;
        const float nl = -logf(1.0f - p + EPSF) * p * p * (q2 * q2);
        cl += (pl + nl) * mask;
    }
    #pragma unroll
    for (int m = 32; m >= 1; m >>= 1) {
        cl  += __shfl_xor(cl,  m, 64);
        wl  += __shfl_xor(wl,  m, 64);
        ol  += __shfl_xor(ol,  m, 64);
        cnt += __shfl_xor(cnt, m, 64);
    }
    if ((tid & 63) == 0) {
        const int w = tid >> 6;
        s_red[w][0] = cl; s_red[w][1] = wl; s_red[w][2] = ol; s_red[w][3] = cnt;
    }
    __syncthreads();
    if (tid == 0) {
        float a = 0, b2 = 0, c = 0, d = 0;
        for (int w = 0; w < 4; ++w) {
            a += s_red[w][0]; b2 += s_red[w][1]; c += s_red[w][2]; d += s_red[w][3];
        }
        partials[b * 4 + 0] = a; partials[b * 4 + 1] = b2;
        partials[b * 4 + 2] = c; partials[b * 4 + 3] = d;
    }
}

// ---------------- Kernel C: local-max filter + exact top-100 + finalize -----
// 512 threads: 4 elems/thread per bitonic substage. Block 0's first wave also
// reduces the loss partials (replaces the separate finalize launch).
__global__ __launch_bounds__(512) void topk_kernel(
    const float* __restrict__ cp, const float* __restrict__ wp,
    const float* __restrict__ op, const float* __restrict__ partials,
    float* __restrict__ out)
{
    __shared__ unsigned long long keys[TT];
    const int b = blockIdx.x;
    const int tid = threadIdx.x;
    const float* row = cp + b * TT;

    for (int t = tid; t < TT; t += 512) {
        const float p = row[t];
        const float l = (t > 0) ? row[t - 1] : -1.0f;       // pad = -inf; cp>=0 so -1 works
        const float r = (t < TT - 1) ? row[t + 1] : -1.0f;
        const float hm = fmaxf(p, fmaxf(l, r));
        const float v = (hm == p) ? p : 0.0f;
        // v >= 0 -> IEEE bits are order-monotonic. Tie-break: lowest index first.
        keys[t] = ((unsigned long long)__float_as_uint(v) << 32)
                | (unsigned int)(0xFFFFFFFFu - (unsigned int)t);
    }
    __syncthreads();

    // bitonic sort, descending
    for (int k = 2; k <= TT; k <<= 1) {
        for (int j = k >> 1; j >= 1; j >>= 1) {
            for (int i = tid; i < TT; i += 512) {
                const int p = i ^ j;
                if (p > i) {
                    const bool desc = ((i & k) == 0);
                    const unsigned long long a = keys[i], bk = keys[p];
                    const bool sw = desc ? (a < bk) : (a > bk);
                    if (sw) { keys[i] = bk; keys[p] = a; }
                }
            }
            __syncthreads();
        }
    }

    if (tid < TOPK_N) {
        const unsigned long long kk = keys[tid];
        const int idx = (int)(0xFFFFFFFFu - (unsigned int)kk);
        const float score = __uint_as_float((unsigned int)(kk >> 32));
        const float off = fmaxf(op[b * TT + idx], 0.0f);
        const float center = (float)idx + off;
        const float win = fmaxf(wp[b * TT + idx], 0.0f);
        const float lo = fminf(fmaxf(center - win * 0.5f, 0.0f), (float)TT - 1.0f) * 2.0f;
        const float hi = fminf(fmaxf(center + win * 0.5f, 0.0f), (float)TT - 1.0f) * 2.0f + 2.0f;
        float* o = out + (b * TOPK_N + tid) * 3;
        o[0] = lo; o[1] = hi; o[2] = score;
    }

    // finalize (block 0, wave 0): sum 64x4 partials, write 3 scalar losses
    if (b == 0 && tid < 64) {
        float cl  = partials[tid * 4 + 0];
        float wl  = partials[tid * 4 + 1];
        float ol  = partials[tid * 4 + 2];
        float cnt = partials[tid * 4 + 3];
        #pragma unroll
        for (int m = 32; m >= 1; m >>= 1) {
            cl  += __shfl_xor(cl,  m, 64);
            wl  += __shfl_xor(wl,  m, 64);
            ol  += __shfl_xor(ol,  m, 64);
            cnt += __shfl_xor(cnt, m, 64);
        }
        if (tid == 0) {
            out[BB * TOPK_N * 3 + 0] = cl / cnt;
            out[BB * TOPK_N * 3 + 1] = 0.1f * wl / cnt;
            out[BB * TOPK_N * 3 + 2] = ol / cnt;
        }
    }
}

extern "C" void kernel_launch(void* const* d_in, const int* in_sizes, int n_in,
                              void* d_out, int out_size, void* d_ws, size_t ws_size,
                              hipStream_t stream) {
    const float* x   = (const float*)d_in[0];
    const float* wc  = (const float*)d_in[1];
    const float* bc  = (const float*)d_in[2];
    const float* ww  = (const float*)d_in[3];
    const float* bw  = (const float*)d_in[4];
    const float* wo  = (const float*)d_in[5];
    const float* bo  = (const float*)d_in[6];
    const float* sal = (const float*)d_in[7];
    const float* bnd = (const float*)d_in[8];
    float* out = (float*)d_out;

    float* ws = (float*)d_ws;
    float* cp = ws;                     // B*T
    float* wp = ws + BB * TT;           // B*T
    float* op = ws + 2 * BB * TT;       // B*T
    float* partials = ws + 3 * BB * TT; // B*4

    // A: 32768 row-groups, 8192 waves -> 4 groups (16 rows) per wave
    preds_kernel<<<2048, 256, 0, stream>>>(x, wc, bc, ww, bw, wo, bo, sal, cp, wp, op);
    targets_kernel<<<BB, 256, 0, stream>>>(bnd, sal, cp, wp, op, partials);
    topk_kernel<<<BB, 512, 0, stream>>>(cp, wp, op, partials, out);
}

// Round 3
// 256.227 us; speedup vs baseline: 1.1507x; 1.0181x over previous
//
#include <hip/hip_runtime.h>
#include <math.h>

#define BB 64
#define TT 2048
#define DD 256
#define MM 20
#define TOPK_N 100
#define EPSF 1e-12f

// ---------------- Kernel A: fused 3-way matvec + activations ----------------
// 16 lanes per row, 4 rows per wave. Memory-bound: reads all of x (134 MB)
// once, coalesced float4. Also zero-inits the finalize ticket (block 0).
__global__ __launch_bounds__(256) void preds_kernel(
    const float* __restrict__ x,
    const float* __restrict__ wc, const float* __restrict__ bc,
    const float* __restrict__ ww, const float* __restrict__ bw,
    const float* __restrict__ wo, const float* __restrict__ bo,
    const float* __restrict__ sal,
    float* __restrict__ cp, float* __restrict__ wp, float* __restrict__ op,
    unsigned int* __restrict__ ticket)
{
    if (blockIdx.x == 0 && threadIdx.x == 0) *ticket = 0u;  // ws is poisoned each iter

    const int lane = threadIdx.x & 63;
    const int sub  = lane >> 4;    // row within the wave's 4-row group
    const int cg   = lane & 15;    // column group
    const int waveg  = blockIdx.x * 4 + (threadIdx.x >> 6);
    const int nwaves = gridDim.x * 4;

    float4 wc4[4], ww4[4], wo4[4];
    #pragma unroll
    for (int k = 0; k < 4; ++k) {
        wc4[k] = ((const float4*)wc)[k * 16 + cg];
        ww4[k] = ((const float4*)ww)[k * 16 + cg];
        wo4[k] = ((const float4*)wo)[k * 16 + cg];
    }
    const float bcs = bc[0], bws = bw[0], bos = bo[0];

    const int ngroups = BB * TT / 4;   // 32768 groups of 4 rows
    for (int g = waveg; g < ngroups; g += nwaves) {
        const int row = g * 4 + sub;
        const float4* xr = (const float4*)(x + (size_t)row * DD);
        float sc = 0.0f, sw = 0.0f, so = 0.0f;
        #pragma unroll
        for (int k = 0; k < 4; ++k) {
            const float4 x4 = xr[k * 16 + cg];
            sc += x4.x * wc4[k].x + x4.y * wc4[k].y + x4.z * wc4[k].z + x4.w * wc4[k].w;
            sw += x4.x * ww4[k].x + x4.y * ww4[k].y + x4.z * ww4[k].z + x4.w * ww4[k].w;
            so += x4.x * wo4[k].x + x4.y * wo4[k].y + x4.z * wo4[k].z + x4.w * wo4[k].w;
        }
        #pragma unroll
        for (int m = 8; m >= 1; m >>= 1) {   // butterfly within 16-lane group
            sc += __shfl_xor(sc, m, 64);
            sw += __shfl_xor(sw, m, 64);
            so += __shfl_xor(so, m, 64);
        }
        if (cg == 0) {
            const float mask = (sal[row] >= 0.0f) ? 1.0f : 0.0f;
            const float s = 1.0f / (1.0f + expf(-(sc + bcs)));
            cp[row] = s * mask;
            wp[row] = sw + bws;
            op[row] = so + bos;
        }
    }
}

// ---------------- Kernel B: targets + loss + topk + finalize (one per b) ----
__global__ __launch_bounds__(256) void fused_kernel(
    const float* __restrict__ boundary, const float* __restrict__ sal,
    const float* __restrict__ cp, const float* __restrict__ wp,
    const float* __restrict__ op, float* __restrict__ partials,
    unsigned int* __restrict__ ticket, float* __restrict__ out)
{
    __shared__ int   s_ci[MM];
    __shared__ float s_win[MM], s_off[MM], s_sig[MM];
    __shared__ int   s_rad[MM], s_valid[MM], s_last[MM];
    __shared__ float s_red[4][4];
    __shared__ unsigned long long keys[TT];
    __shared__ unsigned long long cand[TT];
    __shared__ int s_nz;
    __shared__ int s_islast;

    const int b = blockIdx.x;
    const int tid = threadIdx.x;
    const float* row = cp + b * TT;

    // --- object prep ---
    if (tid == 0) s_nz = 0;
    if (tid < MM) {
        const float b0 = boundary[(b * MM + tid) * 2 + 0];
        const float b1 = boundary[(b * MM + tid) * 2 + 1];
        const int v = (b0 != -1.0f) ? 1 : 0;
        const float b0c = b0 * 0.5f;
        const float b1c = (b1 - 2.0f) * 0.5f;
        const float c = fminf((b0c + b1c) * 0.5f, (float)TT - 0.5f);
        const float w = b1c - b0c;
        const int r = (int)(w * 0.2f);              // trunc like .astype(int32)
        const float sg = ((float)r + 1.0f) * 0.2f;
        const int ci = (int)c;
        s_ci[tid] = ci; s_win[tid] = w; s_off[tid] = c - (float)ci;
        s_sig[tid] = sg; s_rad[tid] = r; s_valid[tid] = v;
    }
    __syncthreads();
    if (tid < MM) {
        int last = s_valid[tid];
        if (last) {  // numpy fancy assignment: last duplicate object wins
            for (int m2 = tid + 1; m2 < MM; ++m2)
                if (s_valid[m2] && s_ci[m2] == s_ci[tid]) { last = 0; break; }
        }
        s_last[tid] = last;
    }
    __syncthreads();

    // --- single pass over t: peak-filter key build + compaction + center loss
    float cl = 0.0f, wl = 0.0f, ol = 0.0f, cnt = 0.0f;
    if (tid < MM) {
        if (s_valid[tid]) cnt = 1.0f;
        if (s_last[tid]) {
            const int t = s_ci[tid];
            wl = fabsf(wp[b * TT + t] - s_win[tid]);
            ol = fabsf(op[b * TT + t] - s_off[tid]);
        }
    }
    for (int t = tid; t < TT; t += 256) {
        const float p = row[t];
        const float l = (t > 0) ? row[t - 1] : -1.0f;
        const float r = (t < TT - 1) ? row[t + 1] : -1.0f;
        const float hm = fmaxf(p, fmaxf(l, r));
        const float v = (hm == p) ? p : 0.0f;
        // v >= 0 -> IEEE bits order-monotonic; tie-break lowest index first.
        const unsigned long long key =
            ((unsigned long long)__float_as_uint(v) << 32)
          | (unsigned int)(0xFFFFFFFFu - (unsigned int)t);
        keys[t] = key;
        if (v != 0.0f) {
            const int pos = atomicAdd(&s_nz, 1);   // unordered append; key has idx
            cand[pos] = key;
        }
        // center loss at this t
        float ctgt = 0.0f;
        for (int m = 0; m < MM; ++m) {
            if (!s_valid[m]) continue;
            const int d = t - s_ci[m];
            const int ad = d < 0 ? -d : d;
            if (ad <= s_rad[m]) {
                const float df = (float)d;
                const float sg = s_sig[m];
                const float g = expf(-(df * df) / (2.0f * sg * sg));
                ctgt = fmaxf(ctgt, g);
            }
        }
        const float mask = (sal[b * TT + t] >= 0.0f) ? 1.0f : 0.0f;
        const float pos = (ctgt == 1.0f) ? 1.0f : 0.0f;
        const float om = 1.0f - p;
        const float pl = -logf(p + EPSF) * om * om * pos;
        const float q = 1.0f - ctgt;
        const float q2 = q * q;
        const float nl = -logf(1.0f - p + EPSF) * p * p * (q2 * q2);
        cl += (pl + nl) * mask;
    }
    // block reduce losses (same order as R2 -> bit-identical)
    #pragma unroll
    for (int m = 32; m >= 1; m >>= 1) {
        cl  += __shfl_xor(cl,  m, 64);
        wl  += __shfl_xor(wl,  m, 64);
        ol  += __shfl_xor(ol,  m, 64);
        cnt += __shfl_xor(cnt, m, 64);
    }
    if ((tid & 63) == 0) {
        const int w = tid >> 6;
        s_red[w][0] = cl; s_red[w][1] = wl; s_red[w][2] = ol; s_red[w][3] = cnt;
    }
    __syncthreads();
    if (tid == 0) {
        float a = 0, b2 = 0, c = 0, d = 0;
        for (int w = 0; w < 4; ++w) {
            a += s_red[w][0]; b2 += s_red[w][1]; c += s_red[w][2]; d += s_red[w][3];
        }
        partials[b * 4 + 0] = a; partials[b * 4 + 1] = b2;
        partials[b * 4 + 2] = c; partials[b * 4 + 3] = d;
    }

    // --- sort: compact path (nz >= 100) or full fallback ---
    const int nz = s_nz;  // stable after the __syncthreads above
    unsigned long long* arr;
    int n;
    if (nz >= TOPK_N) {
        n = 128;
        while (n < nz) n <<= 1;
        for (int i = nz + tid; i < n; i += 256) cand[i] = 0ull;  // pad sorts below real keys
        arr = cand;
    } else {
        n = TT;        // zeros may enter top-k; full array preserves their index order
        arr = keys;
    }
    __syncthreads();
    for (int k = 2; k <= n; k <<= 1) {
        for (int j = k >> 1; j >= 1; j >>= 1) {
            for (int i = tid; i < n; i += 256) {
                const int p = i ^ j;
                if (p > i) {
                    const bool desc = ((i & k) == 0);
                    const unsigned long long a = arr[i], bk = arr[p];
                    const bool sw = desc ? (a < bk) : (a > bk);
                    if (sw) { arr[i] = bk; arr[p] = a; }
                }
            }
            __syncthreads();
        }
    }

    if (tid < TOPK_N) {
        const unsigned long long kk = arr[tid];
        const int idx = (int)(0xFFFFFFFFu - (unsigned int)kk);
        const float score = __uint_as_float((unsigned int)(kk >> 32));
        const float off = fmaxf(op[b * TT + idx], 0.0f);
        const float center = (float)idx + off;
        const float win = fmaxf(wp[b * TT + idx], 0.0f);
        const float lo = fminf(fmaxf(center - win * 0.5f, 0.0f), (float)TT - 1.0f) * 2.0f;
        const float hi = fminf(fmaxf(center + win * 0.5f, 0.0f), (float)TT - 1.0f) * 2.0f + 2.0f;
        float* o = out + (b * TOPK_N + tid) * 3;
        o[0] = lo; o[1] = hi; o[2] = score;
    }

    // --- finalize: last block to arrive reduces the 64x4 partials ---
    __threadfence();
    if (tid == 0) {
        const unsigned int prev = atomicAdd(ticket, 1u);
        s_islast = (prev == (unsigned int)(BB - 1)) ? 1 : 0;
    }
    __syncthreads();
    if (s_islast) {
        __threadfence();
        if (tid < 64) {
            const volatile float* pp = (const volatile float*)partials;
            float fcl  = pp[tid * 4 + 0];
            float fwl  = pp[tid * 4 + 1];
            float fol  = pp[tid * 4 + 2];
            float fcnt = pp[tid * 4 + 3];
            #pragma unroll
            for (int m = 32; m >= 1; m >>= 1) {
                fcl  += __shfl_xor(fcl,  m, 64);
                fwl  += __shfl_xor(fwl,  m, 64);
                fol  += __shfl_xor(fol,  m, 64);
                fcnt += __shfl_xor(fcnt, m, 64);
            }
            if (tid == 0) {
                out[BB * TOPK_N * 3 + 0] = fcl / fcnt;
                out[BB * TOPK_N * 3 + 1] = 0.1f * fwl / fcnt;
                out[BB * TOPK_N * 3 + 2] = fol / fcnt;
            }
        }
    }
}

extern "C" void kernel_launch(void* const* d_in, const int* in_sizes, int n_in,
                              void* d_out, int out_size, void* d_ws, size_t ws_size,
                              hipStream_t stream) {
    const float* x   = (const float*)d_in[0];
    const float* wc  = (const float*)d_in[1];
    const float* bc  = (const float*)d_in[2];
    const float* ww  = (const float*)d_in[3];
    const float* bw  = (const float*)d_in[4];
    const float* wo  = (const float*)d_in[5];
    const float* bo  = (const float*)d_in[6];
    const float* sal = (const float*)d_in[7];
    const float* bnd = (const float*)d_in[8];
    float* out = (float*)d_out;

    float* ws = (float*)d_ws;
    float* cp = ws;                          // B*T
    float* wp = ws + BB * TT;                // B*T
    float* op = ws + 2 * BB * TT;            // B*T
    float* partials = ws + 3 * BB * TT;      // B*4
    unsigned int* ticket = (unsigned int*)(ws + 3 * BB * TT + 4 * BB);

    preds_kernel<<<2048, 256, 0, stream>>>(x, wc, bc, ww, bw, wo, bo, sal,
                                           cp, wp, op, ticket);
    fused_kernel<<<BB, 256, 0, stream>>>(bnd, sal, cp, wp, op, partials, ticket, out);
}